// Round 2
// baseline (230.201 us; speedup 1.0000x reference)
//
#include <hip/hip_runtime.h>
#include <stdint.h>

typedef __bf16 bf16x8 __attribute__((ext_vector_type(8)));
typedef float f32x4 __attribute__((ext_vector_type(4)));

union U8 { uint32_t d[4]; bf16x8 b; };

__device__ __forceinline__ uint32_t f2u(float x){ union{float f;uint32_t u;} c; c.f=x; return c.u; }
__device__ __forceinline__ float u2f(uint32_t u){ union{float f;uint32_t u;} c; c.u=u; return c.f; }

// truncation split: x = hi + lo + O(2^-16 x); hi,lo bf16 (packed 2-at-a-time)
__device__ __forceinline__ void split_pair(float x0, float x1, uint32_t& hp, uint32_t& lp){
  uint32_t u0=f2u(x0), u1=f2u(x1);
  uint32_t h0=u0&0xFFFF0000u, h1=u1&0xFFFF0000u;
  hp = (u0>>16) | h1;
  float l0 = x0 - u2f(h0), l1 = x1 - u2f(h1);
  lp = (f2u(l0)>>16) | (f2u(l1)&0xFFFF0000u);
}

#define MFMA(a,b,c) __builtin_amdgcn_mfma_f32_16x16x32_bf16(a,b,c,0,0,0)

__launch_bounds__(256, 2)
__global__ void kast_attn(const float* __restrict__ K_, const float* __restrict__ V_,
                          const float* __restrict__ MK_, const float* __restrict__ MV_,
                          float* __restrict__ OUT_) {
  __shared__ char KhB[64*512];   // 64 rows x 256 bf16 (hi), XOR-swizzled
  __shared__ char KlB[64*512];   // lo
  __shared__ float vlds[192];    // 64 x 3 f32

  // XCD-aware decode: all 8 q-blocks of one slice land on the same XCD (bid%8)
  const int bid = blockIdx.x;          // 0..447
  const int s  = ((bid>>6)<<3) | (bid & 7);   // slice 0..55
  const int qb = (bid>>3) & 7;                // q-block 0..7
  const int b = s / 7, t = s % 7;
  const float* qptr = K_ + (size_t)((b*8 + t + 1) * 1024) * 256;
  const float* k1   = K_ + (size_t)((b*8 + t) * 1024) * 256;
  const float* v1   = V_ + (size_t)((b*8 + t) * 1024) * 3;
  const float* k2   = MK_ + (size_t)((b*8 + t) * 512) * 256;
  const float* v2   = MV_ + (size_t)((b*8 + t) * 512) * 3;
  float* outp = OUT_ + (size_t)((b*7 + t) * 1024) * 3;

  const int tid = threadIdx.x;
  const int w = tid >> 6, l = tid & 63;
  const int lj = l & 15, lq = l >> 4;
  const int qrow0 = qb*128 + w*32;

  // ---- load Q fragments (A-frag: row = l&15, k = (l>>4)*8 + j), split hi/lo ----
  bf16x8 qh[2][8], ql[2][8];
#pragma unroll
  for (int rt=0; rt<2; rt++){
    const float* qr = qptr + (size_t)(qrow0 + rt*16 + lj)*256 + lq*8;
#pragma unroll
    for (int kc=0; kc<8; kc++){
      float4 a = *(const float4*)(qr + kc*32);
      float4 c = *(const float4*)(qr + kc*32 + 4);
      U8 hh, ll;
      split_pair(a.x, a.y, hh.d[0], ll.d[0]);
      split_pair(a.z, a.w, hh.d[1], ll.d[1]);
      split_pair(c.x, c.y, hh.d[2], ll.d[2]);
      split_pair(c.z, c.w, hh.d[3], ll.d[3]);
      qh[rt][kc]=hh.b; ql[rt][kc]=ll.b;
    }
  }

  for (int ph=0; ph<2; ph++){
    const float* ks = ph ? k2 : k1;
    const float* vs = ph ? v2 : v1;
    const int ntiles = ph ? 8 : 16;
    // per-lane online-softmax state over this lane's own columns
    float m[2][4], ssum[2][4], o[2][4][3];
#pragma unroll
    for (int rt=0;rt<2;rt++)
#pragma unroll
      for (int r=0;r<4;r++){
        m[rt][r]=-1e30f; ssum[rt][r]=0.f;
        o[rt][r][0]=0.f; o[rt][r][1]=0.f; o[rt][r][2]=0.f;
      }

    for (int nt=0; nt<ntiles; nt++){
      __syncthreads();
      // ---- stage K-tile (64x256 f32 -> bf16 hi/lo, XOR swizzle byte^((row&7)<<4)) ----
      const float* kt = ks + (size_t)nt*64*256;
#pragma unroll 4
      for (int i=0;i<16;i++){
        int f4i = tid + i*256;
        int row = f4i >> 6;
        int col4 = f4i & 63;
        float4 x = *(const float4*)(kt + row*256 + col4*4);
        uint32_t hp0,lp0,hp1,lp1;
        split_pair(x.x,x.y,hp0,lp0);
        split_pair(x.z,x.w,hp1,lp1);
        int boff = row*512 + ((col4*8) ^ ((row&7)<<4));
        *(uint2*)(KhB + boff) = make_uint2(hp0,hp1);
        *(uint2*)(KlB + boff) = make_uint2(lp0,lp1);
      }
      if (tid < 192) vlds[tid] = vs[nt*192 + tid];
      __syncthreads();

      // ---- MFMA: S-tile = Qh*Kh + Qh*Kl + Ql*Kh ----
      f32x4 acc[2][4];
#pragma unroll
      for (int rt=0;rt<2;rt++)
#pragma unroll
        for (int ct=0;ct<4;ct++)
          acc[rt][ct] = (f32x4){0.f,0.f,0.f,0.f};

      const int sx = (l&7)<<4;
#pragma unroll
      for (int ct=0;ct<4;ct++){
        const char* rbh = KhB + (ct*16 + lj)*512;
        const char* rbl = KlB + (ct*16 + lj)*512;
#pragma unroll
        for (int kc=0;kc<8;kc++){
          int bo = (kc*64 + (lq<<4)) ^ sx;
          bf16x8 bh = *(const bf16x8*)(rbh + bo);
          bf16x8 bl = *(const bf16x8*)(rbl + bo);
          acc[0][ct] = MFMA(qh[0][kc], bh, acc[0][ct]);
          acc[1][ct] = MFMA(qh[1][kc], bh, acc[1][ct]);
          acc[0][ct] = MFMA(qh[0][kc], bl, acc[0][ct]);
          acc[1][ct] = MFMA(qh[1][kc], bl, acc[1][ct]);
          acc[0][ct] = MFMA(ql[0][kc], bh, acc[0][ct]);
          acc[1][ct] = MFMA(ql[1][kc], bh, acc[1][ct]);
        }
      }

      // ---- per-lane online softmax + PV (cv=3) ----
      float vv[4][3];
#pragma unroll
      for (int ct=0;ct<4;ct++){
        int c = (ct*16 + lj)*3;
        vv[ct][0]=vlds[c]; vv[ct][1]=vlds[c+1]; vv[ct][2]=vlds[c+2];
      }
#pragma unroll
      for (int rt=0;rt<2;rt++)
#pragma unroll
        for (int r=0;r<4;r++){
          float s0=acc[rt][0][r], s1=acc[rt][1][r], s2=acc[rt][2][r], s3=acc[rt][3][r];
          float tmax = fmaxf(fmaxf(s0,s1),fmaxf(s2,s3));
          float mo = m[rt][r];
          float mn = fmaxf(mo, tmax);
          float sc = __expf(mo - mn);
          float p0=__expf(s0-mn), p1=__expf(s1-mn), p2=__expf(s2-mn), p3=__expf(s3-mn);
          ssum[rt][r] = ssum[rt][r]*sc + ((p0+p1)+(p2+p3));
          o[rt][r][0] = o[rt][r][0]*sc + (p0*vv[0][0]+p1*vv[1][0]) + (p2*vv[2][0]+p3*vv[3][0]);
          o[rt][r][1] = o[rt][r][1]*sc + (p0*vv[0][1]+p1*vv[1][1]) + (p2*vv[2][1]+p3*vv[3][1]);
          o[rt][r][2] = o[rt][r][2]*sc + (p0*vv[0][2]+p1*vv[1][2]) + (p2*vv[2][2]+p3*vv[3][2]);
          m[rt][r]=mn;
        }
    } // nt

    // ---- merge the 16 lanes' partial softmaxes, blend, write ----
    const float coef = ph ? 0.2f : 0.8f;
#pragma unroll
    for (int rt=0;rt<2;rt++)
#pragma unroll
      for (int r=0;r<4;r++){
        float mm = m[rt][r];
        mm = fmaxf(mm, __shfl_xor(mm,1));
        mm = fmaxf(mm, __shfl_xor(mm,2));
        mm = fmaxf(mm, __shfl_xor(mm,4));
        mm = fmaxf(mm, __shfl_xor(mm,8));
        float f = __expf(m[rt][r]-mm);
        float sl = ssum[rt][r]*f;
        float o0=o[rt][r][0]*f, o1=o[rt][r][1]*f, o2=o[rt][r][2]*f;
        sl += __shfl_xor(sl,1); sl += __shfl_xor(sl,2); sl += __shfl_xor(sl,4); sl += __shfl_xor(sl,8);
        o0 += __shfl_xor(o0,1); o0 += __shfl_xor(o0,2); o0 += __shfl_xor(o0,4); o0 += __shfl_xor(o0,8);
        o1 += __shfl_xor(o1,1); o1 += __shfl_xor(o1,2); o1 += __shfl_xor(o1,4); o1 += __shfl_xor(o1,8);
        o2 += __shfl_xor(o2,1); o2 += __shfl_xor(o2,2); o2 += __shfl_xor(o2,4); o2 += __shfl_xor(o2,8);
        if (lj == r){
          int row = qrow0 + rt*16 + lq*4 + r;
          float* op = outp + (size_t)row*3;
          float invs = coef / sl;
          if (ph==0){ op[0]=o0*invs; op[1]=o1*invs; op[2]=o2*invs; }
          else      { op[0]+=o0*invs; op[1]+=o1*invs; op[2]+=o2*invs; }
        }
      }
  } // ph
}

// ground truth = v[:,1:]  (second output, exact copy)
__global__ void kast_gt(const float* __restrict__ V_, float* __restrict__ OUT_){
  int s = blockIdx.x; int b = s/7, t = s%7;
  const float4* src = (const float4*)(V_ + (size_t)(b*8+t+1)*3072);
  float4* dst = (float4*)(OUT_ + 172032 + (size_t)s*3072);
  for (int i=threadIdx.x; i<768; i+=256) dst[i] = src[i];
}

extern "C" void kernel_launch(void* const* d_in, const int* in_sizes, int n_in,
                              void* d_out, int out_size, void* d_ws, size_t ws_size,
                              hipStream_t stream) {
  (void)in_sizes; (void)n_in; (void)d_ws; (void)ws_size; (void)out_size;
  const float* K_  = (const float*)d_in[0];
  const float* V_  = (const float*)d_in[1];
  const float* MK_ = (const float*)d_in[2];
  const float* MV_ = (const float*)d_in[3];
  float* out = (float*)d_out;
  hipLaunchKernelGGL(kast_attn, dim3(448), dim3(256), 0, stream, K_, V_, MK_, MV_, out);
  hipLaunchKernelGGL(kast_gt,   dim3(56),  dim3(256), 0, stream, V_, out);
}

// Round 3
// 217.131 us; speedup vs baseline: 1.0602x; 1.0602x over previous
//
#include <hip/hip_runtime.h>
#include <stdint.h>

typedef _Float16 f16x8 __attribute__((ext_vector_type(8)));
typedef __bf16 bf16x8 __attribute__((ext_vector_type(8)));
typedef float f32x4 __attribute__((ext_vector_type(4)));

#define MFMA_F16(a,b,c) __builtin_amdgcn_mfma_f32_16x16x32_f16(a,b,c,0,0,0)
#define MFMA_BF16(a,b,c) __builtin_amdgcn_mfma_f32_16x16x32_bf16(a,b,c,0,0,0)

// ---------------- helpers ----------------
__device__ __forceinline__ uint32_t f2u(float x){ union{float f;uint32_t u;} c; c.f=x; return c.u; }
__device__ __forceinline__ float u2f(uint32_t u){ union{float f;uint32_t u;} c; c.u=u; return c.f; }

union H4 { uint32_t u[2]; _Float16 h[4]; };
union HU8 { uint32_t u[4]; _Float16 h[8]; f16x8 v; };

// f16 round-to-nearest split: x = hi + lo + O(2^-22 x)
__device__ __forceinline__ void split4_f16(float4 x, uint2& hp, uint2& lp){
  H4 hh, ll;
  hh.h[0] = (_Float16)x.x; hh.h[1] = (_Float16)x.y;
  hh.h[2] = (_Float16)x.z; hh.h[3] = (_Float16)x.w;
  ll.h[0] = (_Float16)(x.x - (float)hh.h[0]);
  ll.h[1] = (_Float16)(x.y - (float)hh.h[1]);
  ll.h[2] = (_Float16)(x.z - (float)hh.h[2]);
  ll.h[3] = (_Float16)(x.w - (float)hh.h[3]);
  hp = make_uint2(hh.u[0], hh.u[1]);
  lp = make_uint2(ll.u[0], ll.u[1]);
}

// bf16 truncation split (fallback kernel)
__device__ __forceinline__ void split_pair(float x0, float x1, uint32_t& hp, uint32_t& lp){
  uint32_t u0=f2u(x0), u1=f2u(x1);
  uint32_t h0=u0&0xFFFF0000u, h1=u1&0xFFFF0000u;
  hp = (u0>>16) | h1;
  float l0 = x0 - u2f(h0), l1 = x1 - u2f(h1);
  lp = (f2u(l0)>>16) | (f2u(l1)&0xFFFF0000u);
}

// =====================================================================
// Main kernel v2: grid 1344 = 56 slices x 8 qb x 3 key-splits.
// Each block: 128 q-rows x 512 keys, 2-pass f16 MFMA, online softmax,
// writes partial (m, s, o0..o2) per q-row to ws.
// =====================================================================
__launch_bounds__(256, 3)
__global__ void kast_attn2(const float* __restrict__ K_, const float* __restrict__ V_,
                           const float* __restrict__ MK_, const float* __restrict__ MV_,
                           float* __restrict__ ws) {
  __shared__ char KhB[32*512];    // 32 keys x 256 f16 hi, XOR-swizzled
  __shared__ char KlB[32*512];    // lo
  __shared__ float vlds[512*3];   // all 512 keys' v, staged once

  // XCD-aware decode: slice s lives on XCD s%8; its 24 blocks share L2
  const int bid = blockIdx.x;          // 0..1343
  const int xcd = bid & 7;
  const int idx = bid >> 3;            // 0..167
  const int grp = idx / 24;            // 0..6
  const int sub = idx - grp*24;        // 0..23
  const int s   = xcd + 8*grp;         // slice 0..55
  const int qb  = sub & 7;             // q-block 0..7
  const int ks  = sub >> 3;            // key-split 0..2
  const int b = s / 7, t = s % 7;

  const float* qptr = K_ + (size_t)((b*8 + t + 1) * 1024) * 256;
  const float* kbase; const float* vbase;
  if (ks < 2){
    kbase = K_ + (size_t)((b*8 + t)*1024 + ks*512) * 256;
    vbase = V_ + (size_t)((b*8 + t)*1024 + ks*512) * 3;
  } else {
    kbase = MK_ + (size_t)((b*8 + t) * 512) * 256;
    vbase = MV_ + (size_t)((b*8 + t) * 512) * 3;
  }

  const int tid = threadIdx.x;
  const int w = tid >> 6, l = tid & 63;
  const int lj = l & 15, lq = l >> 4;
  const int qrow0 = qb*128 + w*32;

  // ---- stage all V (512 x 3 f32) once ----
  for (int i = tid; i < 1536; i += 256) vlds[i] = vbase[i];

  // ---- Q hi fragments (f16 RN), rt=2 row-tiles of 16 ----
  f16x8 qh[2][8];
#pragma unroll
  for (int rt=0; rt<2; rt++){
    const float* qr = qptr + (size_t)(qrow0 + rt*16 + lj)*256 + lq*8;
#pragma unroll
    for (int kc=0; kc<8; kc++){
      float4 a = *(const float4*)(qr + kc*32);
      float4 c = *(const float4*)(qr + kc*32 + 4);
      HU8 hh;
      hh.h[0]=(_Float16)a.x; hh.h[1]=(_Float16)a.y; hh.h[2]=(_Float16)a.z; hh.h[3]=(_Float16)a.w;
      hh.h[4]=(_Float16)c.x; hh.h[5]=(_Float16)c.y; hh.h[6]=(_Float16)c.z; hh.h[7]=(_Float16)c.w;
      qh[rt][kc]=hh.v;
    }
  }

  // per-lane online-softmax state
  float m[2][4], ssum[2][4], o[2][4][3];
#pragma unroll
  for (int rt=0;rt<2;rt++)
#pragma unroll
    for (int r=0;r<4;r++){
      m[rt][r]=-1e30f; ssum[rt][r]=0.f;
      o[rt][r][0]=0.f; o[rt][r][1]=0.f; o[rt][r][2]=0.f;
    }

  for (int nt=0; nt<16; nt++){
    __syncthreads();
    // ---- stage 32-key tile: f32 -> f16 hi/lo, swizzle byte^((row&7)<<4) ----
    const float* kt = kbase + (size_t)nt*32*256;
#pragma unroll
    for (int i=0;i<8;i++){
      int f4i = tid + i*256;           // 0..2047
      int row = f4i >> 6, col4 = f4i & 63;
      float4 x = *(const float4*)(kt + row*256 + col4*4);
      uint2 hp, lp; split4_f16(x, hp, lp);
      int boff = row*512 + ((col4*8) ^ ((row&7)<<4));
      *(uint2*)(KhB + boff) = hp;
      *(uint2*)(KlB + boff) = lp;
    }
    __syncthreads();

    // ---- 2-pass MFMA: S = Qh*Kh + Qh*Kl ----
    f32x4 acc[2][2];
#pragma unroll
    for (int rt=0;rt<2;rt++){ acc[rt][0]=(f32x4){0,0,0,0}; acc[rt][1]=(f32x4){0,0,0,0}; }

    const int sx = (l&7)<<4;
#pragma unroll
    for (int ct=0;ct<2;ct++){
      const char* rbh = KhB + (ct*16 + lj)*512;
      const char* rbl = KlB + (ct*16 + lj)*512;
#pragma unroll
      for (int kc=0;kc<8;kc++){
        int bo = (kc*64 + (lq<<4)) ^ sx;
        f16x8 bh = *(const f16x8*)(rbh + bo);
        f16x8 bl = *(const f16x8*)(rbl + bo);
        acc[0][ct] = MFMA_F16(qh[0][kc], bh, acc[0][ct]);
        acc[1][ct] = MFMA_F16(qh[1][kc], bh, acc[1][ct]);
        acc[0][ct] = MFMA_F16(qh[0][kc], bl, acc[0][ct]);
        acc[1][ct] = MFMA_F16(qh[1][kc], bl, acc[1][ct]);
      }
    }

    // ---- online softmax (2 cols/thread/row) + PV ----
    float vv[2][3];
#pragma unroll
    for (int ct=0;ct<2;ct++){
      int c = (nt*32 + ct*16 + lj)*3;
      vv[ct][0]=vlds[c]; vv[ct][1]=vlds[c+1]; vv[ct][2]=vlds[c+2];
    }
#pragma unroll
    for (int rt=0;rt<2;rt++)
#pragma unroll
      for (int r=0;r<4;r++){
        float s0=acc[rt][0][r], s1=acc[rt][1][r];
        float mo = m[rt][r];
        float mn = fmaxf(mo, fmaxf(s0,s1));
        float sc = __expf(mo - mn);
        float p0 = __expf(s0 - mn), p1 = __expf(s1 - mn);
        ssum[rt][r] = ssum[rt][r]*sc + (p0 + p1);
        o[rt][r][0] = o[rt][r][0]*sc + p0*vv[0][0] + p1*vv[1][0];
        o[rt][r][1] = o[rt][r][1]*sc + p0*vv[0][1] + p1*vv[1][1];
        o[rt][r][2] = o[rt][r][2]*sc + p0*vv[0][2] + p1*vv[1][2];
        m[rt][r]=mn;
      }
  } // nt

  // ---- merge 16 lanes (lj) per row, write partial (m,s,o) ----
#pragma unroll
  for (int rt=0;rt<2;rt++)
#pragma unroll
    for (int r=0;r<4;r++){
      float mm = m[rt][r];
      mm = fmaxf(mm, __shfl_xor(mm,1));
      mm = fmaxf(mm, __shfl_xor(mm,2));
      mm = fmaxf(mm, __shfl_xor(mm,4));
      mm = fmaxf(mm, __shfl_xor(mm,8));
      float f = __expf(m[rt][r]-mm);
      float sl = ssum[rt][r]*f;
      float o0=o[rt][r][0]*f, o1=o[rt][r][1]*f, o2=o[rt][r][2]*f;
      sl += __shfl_xor(sl,1); sl += __shfl_xor(sl,2); sl += __shfl_xor(sl,4); sl += __shfl_xor(sl,8);
      o0 += __shfl_xor(o0,1); o0 += __shfl_xor(o0,2); o0 += __shfl_xor(o0,4); o0 += __shfl_xor(o0,8);
      o1 += __shfl_xor(o1,1); o1 += __shfl_xor(o1,2); o1 += __shfl_xor(o1,4); o1 += __shfl_xor(o1,8);
      o2 += __shfl_xor(o2,1); o2 += __shfl_xor(o2,2); o2 += __shfl_xor(o2,4); o2 += __shfl_xor(o2,8);
      if (lj == 0){
        int prow = qrow0 + rt*16 + lq*4 + r;
        float* pp = ws + ((size_t)(s*3 + ks)*1024 + prow)*5;
        pp[0]=mm; pp[1]=sl; pp[2]=o0; pp[3]=o1; pp[4]=o2;
      }
    }
}

// merge 3 partials per q-row -> blended output
__global__ void kast_merge(const float* __restrict__ ws, float* __restrict__ OUT_){
  int r = blockIdx.x*256 + threadIdx.x;   // 0..57343
  if (r >= 56*1024) return;
  int s = r >> 10, row = r & 1023;
  const float* pa = ws + ((size_t)(s*3+0)*1024 + row)*5;
  const float* pb = ws + ((size_t)(s*3+1)*1024 + row)*5;
  const float* pm = ws + ((size_t)(s*3+2)*1024 + row)*5;
  float ma=pa[0], sa=pa[1], mb=pb[0], sb=pb[1];
  float M = fmaxf(ma,mb);
  float ea = __expf(ma-M), eb = __expf(mb-M);
  float w1 = 0.8f / (sa*ea + sb*eb);
  float w2 = 0.2f / pm[1];
  float* op = OUT_ + (size_t)(s*1024 + row)*3;
  op[0] = (pa[2]*ea + pb[2]*eb)*w1 + pm[2]*w2;
  op[1] = (pa[3]*ea + pb[3]*eb)*w1 + pm[3]*w2;
  op[2] = (pa[4]*ea + pb[4]*eb)*w1 + pm[4]*w2;
}

// =====================================================================
// Fallback (round-2 passing kernel) for the case ws_size is too small
// =====================================================================
__launch_bounds__(256, 2)
__global__ void kast_attn_fb(const float* __restrict__ K_, const float* __restrict__ V_,
                             const float* __restrict__ MK_, const float* __restrict__ MV_,
                             float* __restrict__ OUT_) {
  __shared__ char KhB[64*512];
  __shared__ char KlB[64*512];
  __shared__ float vlds[192];

  const int bid = blockIdx.x;
  const int s  = ((bid>>6)<<3) | (bid & 7);
  const int qb = (bid>>3) & 7;
  const int b = s / 7, t = s % 7;
  const float* qptr = K_ + (size_t)((b*8 + t + 1) * 1024) * 256;
  const float* k1   = K_ + (size_t)((b*8 + t) * 1024) * 256;
  const float* v1   = V_ + (size_t)((b*8 + t) * 1024) * 3;
  const float* k2   = MK_ + (size_t)((b*8 + t) * 512) * 256;
  const float* v2   = MV_ + (size_t)((b*8 + t) * 512) * 3;
  float* outp = OUT_ + (size_t)((b*7 + t) * 1024) * 3;

  const int tid = threadIdx.x;
  const int w = tid >> 6, l = tid & 63;
  const int lj = l & 15, lq = l >> 4;
  const int qrow0 = qb*128 + w*32;

  bf16x8 qh[2][8], ql[2][8];
#pragma unroll
  for (int rt=0; rt<2; rt++){
    const float* qr = qptr + (size_t)(qrow0 + rt*16 + lj)*256 + lq*8;
#pragma unroll
    for (int kc=0; kc<8; kc++){
      float4 a = *(const float4*)(qr + kc*32);
      float4 c = *(const float4*)(qr + kc*32 + 4);
      union { uint32_t d[4]; bf16x8 v; } hh, ll;
      split_pair(a.x, a.y, hh.d[0], ll.d[0]);
      split_pair(a.z, a.w, hh.d[1], ll.d[1]);
      split_pair(c.x, c.y, hh.d[2], ll.d[2]);
      split_pair(c.z, c.w, hh.d[3], ll.d[3]);
      qh[rt][kc]=hh.v; ql[rt][kc]=ll.v;
    }
  }

  for (int ph=0; ph<2; ph++){
    const float* ks = ph ? k2 : k1;
    const float* vs = ph ? v2 : v1;
    const int ntiles = ph ? 8 : 16;
    float m[2][4], ssum[2][4], o[2][4][3];
#pragma unroll
    for (int rt=0;rt<2;rt++)
#pragma unroll
      for (int r=0;r<4;r++){
        m[rt][r]=-1e30f; ssum[rt][r]=0.f;
        o[rt][r][0]=0.f; o[rt][r][1]=0.f; o[rt][r][2]=0.f;
      }

    for (int nt=0; nt<ntiles; nt++){
      __syncthreads();
      const float* kt = ks + (size_t)nt*64*256;
#pragma unroll 4
      for (int i=0;i<16;i++){
        int f4i = tid + i*256;
        int row = f4i >> 6;
        int col4 = f4i & 63;
        float4 x = *(const float4*)(kt + row*256 + col4*4);
        uint32_t hp0,lp0,hp1,lp1;
        split_pair(x.x,x.y,hp0,lp0);
        split_pair(x.z,x.w,hp1,lp1);
        int boff = row*512 + ((col4*8) ^ ((row&7)<<4));
        *(uint2*)(KhB + boff) = make_uint2(hp0,hp1);
        *(uint2*)(KlB + boff) = make_uint2(lp0,lp1);
      }
      if (tid < 192) vlds[tid] = vs[nt*192 + tid];
      __syncthreads();

      f32x4 acc[2][4];
#pragma unroll
      for (int rt=0;rt<2;rt++)
#pragma unroll
        for (int ct=0;ct<4;ct++)
          acc[rt][ct] = (f32x4){0.f,0.f,0.f,0.f};

      const int sx = (l&7)<<4;
#pragma unroll
      for (int ct=0;ct<4;ct++){
        const char* rbh = KhB + (ct*16 + lj)*512;
        const char* rbl = KlB + (ct*16 + lj)*512;
#pragma unroll
        for (int kc=0;kc<8;kc++){
          int bo = (kc*64 + (lq<<4)) ^ sx;
          bf16x8 bh = *(const bf16x8*)(rbh + bo);
          bf16x8 bl = *(const bf16x8*)(rbl + bo);
          acc[0][ct] = MFMA_BF16(qh[0][kc], bh, acc[0][ct]);
          acc[1][ct] = MFMA_BF16(qh[1][kc], bh, acc[1][ct]);
          acc[0][ct] = MFMA_BF16(qh[0][kc], bl, acc[0][ct]);
          acc[1][ct] = MFMA_BF16(qh[1][kc], bl, acc[1][ct]);
          acc[0][ct] = MFMA_BF16(ql[0][kc], bh, acc[0][ct]);
          acc[1][ct] = MFMA_BF16(ql[1][kc], bh, acc[1][ct]);
        }
      }

      float vv[4][3];
#pragma unroll
      for (int ct=0;ct<4;ct++){
        int c = (ct*16 + lj)*3;
        vv[ct][0]=vlds[c]; vv[ct][1]=vlds[c+1]; vv[ct][2]=vlds[c+2];
      }
#pragma unroll
      for (int rt=0;rt<2;rt++)
#pragma unroll
        for (int r=0;r<4;r++){
          float s0=acc[rt][0][r], s1=acc[rt][1][r], s2=acc[rt][2][r], s3=acc[rt][3][r];
          float tmax = fmaxf(fmaxf(s0,s1),fmaxf(s2,s3));
          float mo = m[rt][r];
          float mn = fmaxf(mo, tmax);
          float sc = __expf(mo - mn);
          float p0=__expf(s0-mn), p1=__expf(s1-mn), p2=__expf(s2-mn), p3=__expf(s3-mn);
          ssum[rt][r] = ssum[rt][r]*sc + ((p0+p1)+(p2+p3));
          o[rt][r][0] = o[rt][r][0]*sc + (p0*vv[0][0]+p1*vv[1][0]) + (p2*vv[2][0]+p3*vv[3][0]);
          o[rt][r][1] = o[rt][r][1]*sc + (p0*vv[0][1]+p1*vv[1][1]) + (p2*vv[2][1]+p3*vv[3][1]);
          o[rt][r][2] = o[rt][r][2]*sc + (p0*vv[0][2]+p1*vv[1][2]) + (p2*vv[2][2]+p3*vv[3][2]);
          m[rt][r]=mn;
        }
    }

    const float coef = ph ? 0.2f : 0.8f;
#pragma unroll
    for (int rt=0;rt<2;rt++)
#pragma unroll
      for (int r=0;r<4;r++){
        float mm = m[rt][r];
        mm = fmaxf(mm, __shfl_xor(mm,1));
        mm = fmaxf(mm, __shfl_xor(mm,2));
        mm = fmaxf(mm, __shfl_xor(mm,4));
        mm = fmaxf(mm, __shfl_xor(mm,8));
        float f = __expf(m[rt][r]-mm);
        float sl = ssum[rt][r]*f;
        float o0=o[rt][r][0]*f, o1=o[rt][r][1]*f, o2=o[rt][r][2]*f;
        sl += __shfl_xor(sl,1); sl += __shfl_xor(sl,2); sl += __shfl_xor(sl,4); sl += __shfl_xor(sl,8);
        o0 += __shfl_xor(o0,1); o0 += __shfl_xor(o0,2); o0 += __shfl_xor(o0,4); o0 += __shfl_xor(o0,8);
        o1 += __shfl_xor(o1,1); o1 += __shfl_xor(o1,2); o1 += __shfl_xor(o1,4); o1 += __shfl_xor(o1,8);
        o2 += __shfl_xor(o2,1); o2 += __shfl_xor(o2,2); o2 += __shfl_xor(o2,4); o2 += __shfl_xor(o2,8);
        if (lj == 0){
          int row = qrow0 + rt*16 + lq*4 + r;
          float* op = outp + (size_t)row*3;
          float invs = coef / sl;
          if (ph==0){ op[0]=o0*invs; op[1]=o1*invs; op[2]=o2*invs; }
          else      { op[0]+=o0*invs; op[1]+=o1*invs; op[2]+=o2*invs; }
        }
      }
  }
}

// ground truth = v[:,1:] (second output, exact copy)
__global__ void kast_gt(const float* __restrict__ V_, float* __restrict__ OUT_){
  int s = blockIdx.x; int b = s/7, t = s%7;
  const float4* src = (const float4*)(V_ + (size_t)(b*8+t+1)*3072);
  float4* dst = (float4*)(OUT_ + 172032 + (size_t)s*3072);
  for (int i=threadIdx.x; i<768; i+=256) dst[i] = src[i];
}

extern "C" void kernel_launch(void* const* d_in, const int* in_sizes, int n_in,
                              void* d_out, int out_size, void* d_ws, size_t ws_size,
                              hipStream_t stream) {
  (void)in_sizes; (void)n_in; (void)out_size;
  const float* K_  = (const float*)d_in[0];
  const float* V_  = (const float*)d_in[1];
  const float* MK_ = (const float*)d_in[2];
  const float* MV_ = (const float*)d_in[3];
  float* out = (float*)d_out;

  const size_t need = (size_t)56*3*1024*5*sizeof(float);   // 3.44 MB partials
  if (ws_size >= need){
    float* ws = (float*)d_ws;
    hipLaunchKernelGGL(kast_attn2, dim3(1344), dim3(256), 0, stream, K_, V_, MK_, MV_, ws);
    hipLaunchKernelGGL(kast_merge, dim3(224),  dim3(256), 0, stream, ws, out);
  } else {
    hipLaunchKernelGGL(kast_attn_fb, dim3(448), dim3(256), 0, stream, K_, V_, MK_, MV_, out);
  }
  hipLaunchKernelGGL(kast_gt, dim3(56), dim3(256), 0, stream, V_, out);
}